// Round 9
// baseline (469.603 us; speedup 1.0000x reference)
//
#include <hip/hip_runtime.h>
#include <hip/hip_fp16.h>

constexpr int N = 200000;
constexpr int E = 5000000;
constexpr int F = 16;
constexpr int CAP = 2048;        // LDS col staging per layer block
constexpr int BUCKB = 10;        // bucket = dst >> 10 (1024 nodes/bucket)
constexpr int NBKT = (N + 1023) >> 10;   // 196
constexpr int NB_CH = 512;       // chunk blocks for hist/scatter
constexpr int BANDS = 8;         // src-band radix within each node's neighbor list

// ---- 0: convert x to fp16 ----
__global__ __launch_bounds__(256) void x2h_kernel(const float* __restrict__ x,
                                                  __half* __restrict__ xh) {
    int i = blockIdx.x * 256 + threadIdx.x;
    if (i < N * F / 2) {
        float2 v = reinterpret_cast<const float2*>(x)[i];
        reinterpret_cast<__half2*>(xh)[i] = __floats2half2_rn(v.x, v.y);
    }
}

// ---- 1: per-(bucket, block) histogram of dst ----
__global__ __launch_bounds__(1024) void hist_kernel(const int* __restrict__ dst,
                                                    int* __restrict__ hist) {
    __shared__ int h[NBKT];
    if (threadIdx.x < NBKT) h[threadIdx.x] = 0;
    __syncthreads();
    const int chunk = (E + NB_CH - 1) / NB_CH;
    const int lo = blockIdx.x * chunk, hi = min(E, lo + chunk);
    for (int e = lo + (int)threadIdx.x; e < hi; e += 1024)
        atomicAdd(&h[dst[e] >> BUCKB], 1);
    __syncthreads();
    if (threadIdx.x < NBKT)
        hist[threadIdx.x * NB_CH + blockIdx.x] = h[threadIdx.x];   // bucket-major
}

// ---- 2: exclusive scan of hist (NBKT*NB_CH ints) in place; extract bucket starts ----
__global__ __launch_bounds__(1024) void scan_hist_kernel(int* __restrict__ hist,
                                                         int* __restrict__ bstart) {
    __shared__ int sm[1024];
    const int M = NBKT * NB_CH;
    const int per = (M + 1023) / 1024;
    const int t = threadIdx.x;
    const int lo = t * per, hi = min(M, lo + per);
    int s = 0;
    for (int i = lo; i < hi; i++) s += hist[i];
    sm[t] = s; __syncthreads();
    for (int st = 1; st < 1024; st <<= 1) {
        int v = (t >= st) ? sm[t - st] : 0;
        __syncthreads();
        sm[t] += v;
        __syncthreads();
    }
    int run = sm[t] - s;                      // exclusive base for this thread's range
    for (int i = lo; i < hi; i++) { int v = hist[i]; hist[i] = run; run += v; }
    __syncthreads();
    if (t <= NBKT) bstart[t] = (t < NBKT) ? hist[t * NB_CH] : E;
}

// ---- 3: scatter packed (local_dst<<18 | src) into bucket-major order ----
__global__ __launch_bounds__(1024) void bucket_scatter_kernel(const int* __restrict__ src,
                                                              const int* __restrict__ dst,
                                                              const int* __restrict__ hist,
                                                              unsigned* __restrict__ pairs) {
    __shared__ int cur[NBKT];
    if (threadIdx.x < NBKT) cur[threadIdx.x] = hist[threadIdx.x * NB_CH + blockIdx.x];
    __syncthreads();
    const int chunk = (E + NB_CH - 1) / NB_CH;
    const int lo = blockIdx.x * chunk, hi = min(E, lo + chunk);
    for (int e = lo + (int)threadIdx.x; e < hi; e += 1024) {
        int d = dst[e];
        int p = atomicAdd(&cur[d >> BUCKB], 1);
        pairs[p] = ((unsigned)(d & 1023) << 18) | (unsigned)src[e];
    }
}

// ---- 4: per-bucket CSR with src-band radix: key = (local_dst<<3)|(src>>15) ----
__global__ __launch_bounds__(256) void build_csr_kernel(const unsigned* __restrict__ pairs,
                                                        const int* __restrict__ bstart,
                                                        int* __restrict__ off,
                                                        int* __restrict__ col) {
    __shared__ int cnt[1024 * BANDS];             // 32 KB
    __shared__ int sm[256];
    const int b = blockIdx.x;
    const int p0 = bstart[b], p1 = bstart[b + 1];
    const int nodeBase = b << BUCKB;
    const int t = threadIdx.x;
    for (int i = t; i < 1024 * BANDS; i += 256) cnt[i] = 0;
    __syncthreads();
    for (int j = p0 + t; j < p1; j += 256) {
        unsigned pk = pairs[j];
        int key = (int)(pk >> 18) * BANDS + (int)((pk & 0x3FFFF) >> 15);
        atomicAdd(&cnt[key], 1);
    }
    __syncthreads();
    // exclusive scan of cnt[8192] with 256 threads (32 elems each)
    int loc[32];
    int s = 0;
#pragma unroll
    for (int q = 0; q < 32; q++) { loc[q] = cnt[32 * t + q]; s += loc[q]; }
    sm[t] = s; __syncthreads();
    for (int st = 1; st < 256; st <<= 1) {
        int v = (t >= st) ? sm[t - st] : 0;
        __syncthreads();
        sm[t] += v;
        __syncthreads();
    }
    int run = p0 + sm[t] - s;
#pragma unroll
    for (int q = 0; q < 32; q++) { cnt[32 * t + q] = run; run += loc[q]; }
    __syncthreads();
    const int n0 = nodeBase + 4 * t;
#pragma unroll
    for (int q = 0; q < 4; q++)
        if (n0 + q < N) off[n0 + q] = cnt[(4 * t + q) * BANDS];
    if (b == gridDim.x - 1 && t == 255) off[N] = p1;
    __syncthreads();
    for (int j = p0 + t; j < p1; j += 256) {
        unsigned pk = pairs[j];
        int srcv = (int)(pk & 0x3FFFF);
        int key = (int)(pk >> 18) * BANDS + (srcv >> 15);
        int p = atomicAdd(&cnt[key], 1);
        col[p] = srcv;
    }
}

// ---- fused gather + SAGE update (+optional fc1 / fc2+softmax), fp16 h ----
// block = 256 threads = 16 nodes x 16 feature-lanes. Gather phase: 4-lane teams,
// each lane loads ushort4 (8B) -> one wave instr covers 16 rows; 8-deep unroll
// -> 128 rows in flight per wave.
__global__ __launch_bounds__(256) void layer_kernel(
    const __half* __restrict__ hin, __half* __restrict__ hout,
    const int* __restrict__ off, const int* __restrict__ col,
    const float* __restrict__ Wl, const float* __restrict__ bl,
    const float* __restrict__ Wr,
    const float* __restrict__ fcW, const float* __restrict__ fcb,
    int mode,                 // 0 = plain, 1 = +fc1+relu, 2 = final (slice8+fc2+relu+softmax)
    float* __restrict__ outp) {
    __shared__ int cols[CAP];
    __shared__ float Mt[16][17], Xt[16][17];
    const int tid = threadIdx.x;
    const int nb = blockIdx.x * 16;
    const int base = off[nb];
    const int tot = off[nb + 16] - base;
    const int stot = min(tot, CAP);
    for (int j = tid; j < stot; j += 256)           // coalesced stage of this block's col range
        cols[j] = col[base + j];
    __syncthreads();

    const int ty = tid >> 4;
    const int k  = tid & 15;
    const int n  = nb + ty;
    const int o0 = off[n] - base, o1 = off[n + 1] - base;

    const int sub = k >> 2;   // 0..3: which edge of the quad this lane serves
    const int qf  = k & 3;    // feature quad: features 4qf..4qf+3

    float4 A0 = {0,0,0,0}, A1 = {0,0,0,0}, A2 = {0,0,0,0}, A3 = {0,0,0,0};
    float4 A4 = {0,0,0,0}, A5 = {0,0,0,0}, A6 = {0,0,0,0}, A7 = {0,0,0,0};
    const int lim = min(o1, CAP);

#define GLOAD(ACC, JJ)                                                          \
    {                                                                           \
        int c_ = cols[(JJ)];                                                    \
        uint2 u_ = *reinterpret_cast<const uint2*>(&hin[c_ * F + qf * 4]);      \
        float2 f0_ = __half22float2(*reinterpret_cast<__half2*>(&u_.x));        \
        float2 f1_ = __half22float2(*reinterpret_cast<__half2*>(&u_.y));        \
        ACC.x += f0_.x; ACC.y += f0_.y; ACC.z += f1_.x; ACC.w += f1_.y;         \
    }

    int j = o0 + sub;
    for (; j + 28 < lim; j += 32) {
        GLOAD(A0, j);      GLOAD(A1, j + 4);  GLOAD(A2, j + 8);  GLOAD(A3, j + 12);
        GLOAD(A4, j + 16); GLOAD(A5, j + 20); GLOAD(A6, j + 24); GLOAD(A7, j + 28);
    }
    for (; j < lim; j += 4) GLOAD(A0, j);
#undef GLOAD
    // global fallback if block's col range overflowed CAP (statistically never)
    for (int jg = (lim > o0 ? (lim - o0 + 3) / 4 * 4 + o0 : o0) + sub; jg < o1; jg += 4) {
        int c_ = col[base + jg];
        uint2 u_ = *reinterpret_cast<const uint2*>(&hin[c_ * F + qf * 4]);
        float2 f0_ = __half22float2(*reinterpret_cast<__half2*>(&u_.x));
        float2 f1_ = __half22float2(*reinterpret_cast<__half2*>(&u_.y));
        A0.x += f0_.x; A0.y += f0_.y; A0.z += f1_.x; A0.w += f1_.y;
    }

    float4 acc;
    acc.x = ((A0.x + A1.x) + (A2.x + A3.x)) + ((A4.x + A5.x) + (A6.x + A7.x));
    acc.y = ((A0.y + A1.y) + (A2.y + A3.y)) + ((A4.y + A5.y) + (A6.y + A7.y));
    acc.z = ((A0.z + A1.z) + (A2.z + A3.z)) + ((A4.z + A5.z) + (A6.z + A7.z));
    acc.w = ((A0.w + A1.w) + (A2.w + A3.w)) + ((A4.w + A5.w) + (A6.w + A7.w));
    // combine the 4 sub-teams (lanes differing in bits 2..3 of k)
    acc.x += __shfl_xor(acc.x, 4); acc.y += __shfl_xor(acc.y, 4);
    acc.z += __shfl_xor(acc.z, 4); acc.w += __shfl_xor(acc.w, 4);
    acc.x += __shfl_xor(acc.x, 8); acc.y += __shfl_xor(acc.y, 8);
    acc.z += __shfl_xor(acc.z, 8); acc.w += __shfl_xor(acc.w, 8);

    const float inv = 1.f / fmaxf((float)(o1 - o0), 1.f);
    if (sub == 0) {
        Mt[ty][4 * qf + 0] = acc.x * inv;
        Mt[ty][4 * qf + 1] = acc.y * inv;
        Mt[ty][4 * qf + 2] = acc.z * inv;
        Mt[ty][4 * qf + 3] = acc.w * inv;
    }
    Xt[ty][k] = __half2float(hin[n * F + k]);
    __syncthreads();

    float a = bl[k];
#pragma unroll
    for (int kk = 0; kk < F; kk++)
        a = fmaf(Mt[ty][kk], Wl[k * F + kk], fmaf(Xt[ty][kk], Wr[k * F + kk], a));
    float o = fmaxf(a, 0.f);   // relu follows every SAGE layer in this graph

    if (mode == 0) { hout[n * F + k] = __float2half(o); return; }

    __syncthreads();
    Mt[ty][k] = o;
    __syncthreads();

    if (mode == 1) {
        float a2f = fcb[k];
#pragma unroll
        for (int kk = 0; kk < F; kk++) a2f = fmaf(Mt[ty][kk], fcW[k * F + kk], a2f);
        hout[n * F + k] = __float2half(fmaxf(a2f, 0.f));
        return;
    }

    // final: slice [:, :8] -> fc2 (8x8) -> relu -> softmax over 8
    if (k < 8) {
        float a2f = fcb[k];
#pragma unroll
        for (int kk = 0; kk < 8; kk++) a2f = fmaf(Mt[ty][kk], fcW[k * 8 + kk], a2f);
        float u = fmaxf(a2f, 0.f);
        float mx = u;
        mx = fmaxf(mx, __shfl_xor(mx, 1));
        mx = fmaxf(mx, __shfl_xor(mx, 2));
        mx = fmaxf(mx, __shfl_xor(mx, 4));
        float ex = __expf(u - mx);
        float sum = ex;
        sum += __shfl_xor(sum, 1);
        sum += __shfl_xor(sum, 2);
        sum += __shfl_xor(sum, 4);
        outp[n * 8 + k] = ex / sum;
    }
}

extern "C" void kernel_launch(void* const* d_in, const int* in_sizes, int n_in,
                              void* d_out, int out_size, void* d_ws, size_t ws_size,
                              hipStream_t stream) {
    const float* x = (const float*)d_in[0];
    const int* edge = (const int*)d_in[1];   // int64 inputs arrive as int32
    const int* src = edge;
    const int* dst = edge + E;
    const float* c1_Wl = (const float*)d_in[2];
    const float* c1_bl = (const float*)d_in[3];
    const float* c1_Wr = (const float*)d_in[4];
    const float* c2_Wl = (const float*)d_in[5];
    const float* c2_bl = (const float*)d_in[6];
    const float* c2_Wr = (const float*)d_in[7];
    const float* fc1_W = (const float*)d_in[8];
    const float* fc1_b = (const float*)d_in[9];
    const float* fc2_W = (const float*)d_in[10];
    const float* fc2_b = (const float*)d_in[11];
    float* out = (float*)d_out;

    // workspace: pairs 20MB + col 20MB + off + hist ~0.4MB + xh/hA/hB 19.2MB  (~61MB)
    char* w = (char*)d_ws;
    unsigned* pairs = (unsigned*)w;    w += (size_t)E * 4;
    int* col  = (int*)w;               w += (size_t)E * 4;
    int* off  = (int*)w;               w += (size_t)(N + 1) * 4;
    int* hist = (int*)w;               w += (size_t)NBKT * NB_CH * 4;
    int* bstart = (int*)w;             w += (size_t)(NBKT + 4) * 4;
    __half* xh = (__half*)w;           w += (size_t)N * F * 2;
    __half* hA = (__half*)w;           w += (size_t)N * F * 2;
    __half* hB = (__half*)w;           w += (size_t)N * F * 2;

    const int nblk_nodes = N / 16;                   // 12500

    // ---- CSR build (bucket counting sort; off computed in-bucket) + x fp16 convert ----
    x2h_kernel<<<(N * F / 2 + 255) / 256, 256, 0, stream>>>(x, xh);
    hist_kernel<<<NB_CH, 1024, 0, stream>>>(dst, hist);
    scan_hist_kernel<<<1, 1024, 0, stream>>>(hist, bstart);
    bucket_scatter_kernel<<<NB_CH, 1024, 0, stream>>>(src, dst, hist, pairs);
    build_csr_kernel<<<NBKT, 256, 0, stream>>>(pairs, bstart, off, col);

    // ---- 4 fused layers (ping-pong hA/hB) ----
    layer_kernel<<<nblk_nodes, 256, 0, stream>>>(xh, hA, off, col,
        c1_Wl, c1_bl, c1_Wr, nullptr, nullptr, 0, nullptr);
    layer_kernel<<<nblk_nodes, 256, 0, stream>>>(hA, hB, off, col,
        c1_Wl + F * F, c1_bl + F, c1_Wr + F * F, fc1_W, fc1_b, 1, nullptr);
    layer_kernel<<<nblk_nodes, 256, 0, stream>>>(hB, hA, off, col,
        c2_Wl, c2_bl, c2_Wr, nullptr, nullptr, 0, nullptr);
    layer_kernel<<<nblk_nodes, 256, 0, stream>>>(hA, nullptr, off, col,
        c2_Wl + F * F, c2_bl + F, c2_Wr + F * F, fc2_W, fc2_b, 2, out);
}